// Round 17
// baseline (112.119 us; speedup 1.0000x reference)
//
#include <hip/hip_runtime.h>
#include <hip/hip_bf16.h>

typedef float f32x4 __attribute__((ext_vector_type(4)));
typedef float f32x2 __attribute__((ext_vector_type(2)));
typedef short s16x8 __attribute__((ext_vector_type(8)));
typedef unsigned short ush4 __attribute__((ext_vector_type(4)));
typedef unsigned u32x4 __attribute__((ext_vector_type(4)));
typedef unsigned u32x2 __attribute__((ext_vector_type(2)));

#define B_ 32
#define C_ 256
#define H_ 56
#define W_ 56
#define HW_ (H_*W_)     // 3136
#define CH_ 14336       // C_*H_ == C_*W_
#define NHT 28          // H_/2 row-tiles per batch
#define CPH 68          // ushort stride scout/swout (8B-aligned b64 frag loads)
#define SGP2 60         // ushort stride for gate tiles [c][w] (120B/row, b64-aligned at w%4==0)
#define CGRP 16         // channels per k_reduce block

// LDS layout (75296 B -> 2 blocks/CU). sg1 aliases scout; sred0/1 alias swout.
#define OFF_SG0   0          // 30720 B (256*60*2)
#define OFF_SCOUT 30720      // 34816 B (256*68*2)  [∪ sg1 30720]
#define OFF_SWOUT 65536      //  8704 B (64*68*2)   [∪ sred0+sred1 8192]
#define OFF_SRED0 65536
#define OFF_SRED1 69632
#define OFF_SHOUT 74240      //   544 B (2*68*4)
#define OFF_SINV0 74784      //   256 B
#define OFF_SINV1 75040      //   256 B
#define SMEM_SZ   75296

// ---------- helpers ----------
__device__ __forceinline__ unsigned short f2bf(float f) {
    unsigned u = __float_as_uint(f);
    u += 0x7fffu + ((u >> 16) & 1u);     // round-to-nearest-even
    return (unsigned short)(u >> 16);
}
__device__ __forceinline__ float bf2f(unsigned short u) {
    return __uint_as_float((unsigned)u << 16);
}
__device__ __forceinline__ f32x4 bf2f4(ush4 u) {
    f32x4 r; r[0] = bf2f(u[0]); r[1] = bf2f(u[1]); r[2] = bf2f(u[2]); r[3] = bf2f(u[3]);
    return r;
}
__device__ __forceinline__ unsigned pkbf(float lo, float hi) {
    __hip_bfloat162 h = __float22bfloat162_rn(make_float2(lo, hi));
    unsigned r;
    __builtin_memcpy(&r, &h, 4);
    return r;
}
__device__ __forceinline__ s16x8 pack8(f32x4 a, f32x4 b) {
    u32x4 t = { pkbf(a[0], a[1]), pkbf(a[2], a[3]), pkbf(b[0], b[1]), pkbf(b[2], b[3]) };
    s16x8 r;
    __builtin_memcpy(&r, &t, 16);
    return r;
}
__device__ __forceinline__ s16x8 cat8(ush4 a, ush4 b) {
    s16x8 r;
    r[0] = (short)a[0]; r[1] = (short)a[1]; r[2] = (short)a[2]; r[3] = (short)a[3];
    r[4] = (short)b[0]; r[5] = (short)b[1]; r[6] = (short)b[2]; r[7] = (short)b[3];
    return r;
}
__device__ __forceinline__ float dpp_shr1(float v) {   // lane i <- v[i-1]; lane0 <- 0 (bound_ctrl)
    return __int_as_float(__builtin_amdgcn_mov_dpp(__float_as_int(v), 0x138, 0xf, 0xf, true));
}
__device__ __forceinline__ float dpp_shl1(float v) {   // lane i <- v[i+1]; lane63 <- 0
    return __int_as_float(__builtin_amdgcn_mov_dpp(__float_as_int(v), 0x130, 0xf, 0xf, true));
}

// ---------- K1: GAP reductions (hierarchical; 1 global atomic per value per block) ----------
__global__ __launch_bounds__(832) void k_reduce(const float* __restrict__ x,
                                                float* __restrict__ gapc,
                                                float* __restrict__ gw,
                                                float* __restrict__ gh) {
    __shared__ float chanpart[13 * CGRP];
    __shared__ float rowsum[H_];
    __shared__ float colsum[W_];
    const int bid = blockIdx.x;
    const int b  = bid >> 4;
    const int c0 = (bid & 15) * CGRP;
    const int tid = threadIdx.x;
    const int lane = tid & 63, wid = tid >> 6;
    if (tid < H_) rowsum[tid] = 0.f;
    else if (tid >= 64 && tid < 64 + W_) colsum[tid - 64] = 0.f;
    __syncthreads();

    const bool act = tid < 784;
    const int j = act ? tid : 0;
    const float* px = x + (size_t)(b * C_ + c0) * HW_ + j * 4;
    f32x4 posacc = {0, 0, 0, 0};
    #pragma unroll 4
    for (int c = 0; c < CGRP; ++c) {
        f32x4 v = {0, 0, 0, 0};
        if (act) v = *(const f32x4*)(px + (size_t)c * HW_);
        posacc += v;
        float s = v[0] + v[1] + v[2] + v[3];
        #pragma unroll
        for (int d = 1; d < 64; d <<= 1) s += __shfl_xor(s, d, 64);
        if (lane == 0) chanpart[wid * CGRP + c] = s;
    }
    if (act) {
        const int h = j / 14, w4 = j % 14;
        atomicAdd(&rowsum[h], posacc[0] + posacc[1] + posacc[2] + posacc[3]);
        atomicAdd(&colsum[w4 * 4 + 0], posacc[0]);
        atomicAdd(&colsum[w4 * 4 + 1], posacc[1]);
        atomicAdd(&colsum[w4 * 4 + 2], posacc[2]);
        atomicAdd(&colsum[w4 * 4 + 3], posacc[3]);
    }
    __syncthreads();
    if (tid < CGRP) {
        float t = 0.f;
        #pragma unroll
        for (int w = 0; w < 13; ++w) t += chanpart[w * CGRP + tid];
        gapc[b * C_ + c0 + tid] = t * (1.f / HW_);
    } else if (tid >= 64 && tid < 64 + H_) {
        atomicAdd(&gh[b * H_ + (tid - 64)], rowsum[tid - 64]);
    } else if (tid >= 128 && tid < 128 + W_) {
        atomicAdd(&gw[b * W_ + (tid - 128)], colsum[tid - 128]);
    }
}

// ---------- conv3d + gated store (templated on h-boundary) ----------
// Lane remap for conv: lane = cg*14 + wq (4 channel-groups x 14 w-quads).
// Each lane: 1 output channel, 4 w positions (f32x4 loads/stores), both rows
// (f32x2 packed accumulators). w+-1 taps from vector components + 2 DPP/row.
template<bool EDGE>
__device__ __forceinline__ void conv_store(
    const float* __restrict__ xb, const float* __restrict__ W3,
    const unsigned short* sg0, const unsigned short* sg1,
    const float* __restrict__ sinv0, const float* __restrict__ sinv1,
    int h0, int cbase, int lane,
    float* __restrict__ outb)
{
    const int cg = lane / 14;              // 0..3 active; 4 for lanes 56-63
    const int wq = lane - cg * 14;         // 0..13
    const bool active = lane < 56;
    const int cgc = (cg < 4) ? cg : 3;     // clamp for always-legal addressing
    const int w0 = wq * 4;

    #pragma unroll 1
    for (int q = 0; q < 4; ++q) {
        const int c = cbase + q * 4 + cgc;          // this lane's output channel
        f32x2 racc[4] = {{0,0},{0,0},{0,0},{0,0}};  // [w-pos j]{row0,row1}
        f32x4 xm0, xm1;
        #pragma unroll
        for (int dz = 0; dz < 3; ++dz) {            // weight channel tap
            const int cc = c + dz - 1;
            const bool cok = (cc >= 0) && (cc < C_) && active;
            const int ccl = cc < 0 ? 0 : (cc > C_ - 1 ? C_ - 1 : cc);
            const float* pc = xb + (size_t)ccl * HW_ + w0;
            #pragma unroll
            for (int jr = 0; jr < 4; ++jr) {
                f32x4 v;
                bool keep = cok;
                if (EDGE) {
                    const int hh = h0 - 1 + jr;
                    keep = keep && (hh >= 0) && (hh < H_);
                    const int hcl = hh < 0 ? 0 : (hh > H_ - 1 ? H_ - 1 : hh);
                    v = *(const f32x4*)(pc + hcl * W_);
                } else {
                    v = *(const f32x4*)(pc + (h0 - 1 + jr) * W_);
                }
                if (!keep) v = (f32x4){0, 0, 0, 0};
                if (dz == 1 && jr == 1) xm0 = v;    // residual rows (center ch)
                if (dz == 1 && jr == 2) xm1 = v;
                float prevw = dpp_shr1(v[3]);       // lane-1's w0+3 == my w0-1
                prevw = (wq == 0) ? 0.f : prevw;    // w=-1 pad / cg boundary
                float nextx = dpp_shl1(v[0]);       // lane+1's w0 == my w0+4
                nextx = (wq == 13) ? 0.f : nextx;   // w=56 pad / cg boundary
                const float vls[4] = { prevw, v[0], v[1], v[2] };
                const float vrs[4] = { v[1], v[2], v[3], nextx };
                if (jr >= 1 && jr <= 2) {           // both rows: packed fma
                    const int wi0 = (dz * 3 + jr) * 3;
                    const int wi1 = (dz * 3 + jr - 1) * 3;
                    const f32x2 wl = {W3[wi0+0], W3[wi1+0]};
                    const f32x2 wc = {W3[wi0+1], W3[wi1+1]};
                    const f32x2 wr = {W3[wi0+2], W3[wi1+2]};
                    #pragma unroll
                    for (int j = 0; j < 4; ++j) {
                        const f32x2 a = {vls[j], vls[j]};
                        const f32x2 m = {v[j], v[j]};
                        const f32x2 z = {vrs[j], vrs[j]};
                        racc[j] = __builtin_elementwise_fma(wl, a,
                                  __builtin_elementwise_fma(wc, m,
                                  __builtin_elementwise_fma(wr, z, racc[j])));
                    }
                } else if (jr == 0) {               // row0 only, dy=0
                    const int wi = (dz * 3 + 0) * 3;
                    #pragma unroll
                    for (int j = 0; j < 4; ++j)
                        racc[j][0] = fmaf(W3[wi], vls[j], fmaf(W3[wi+1], v[j], fmaf(W3[wi+2], vrs[j], racc[j][0])));
                } else {                            // jr==3: row1 only, dy=2
                    const int wi = (dz * 3 + 2) * 3;
                    #pragma unroll
                    for (int j = 0; j < 4; ++j)
                        racc[j][1] = fmaf(W3[wi], vls[j], fmaf(W3[wi+1], v[j], fmaf(W3[wi+2], vrs[j], racc[j][1])));
                }
            }
        }
        if (active) {
            const ush4 g0 = *(const ush4*)&sg0[c * SGP2 + w0];   // 4 gates, b64
            const ush4 g1 = *(const ush4*)&sg1[c * SGP2 + w0];
            const f32x4 i0 = *(const f32x4*)&sinv0[w0];
            const f32x4 i1 = *(const f32x4*)&sinv1[w0];
            f32x4 o0, o1;
            #pragma unroll
            for (int j = 0; j < 4; ++j) {
                o0[j] = fmaf(racc[j][0], bf2f(g0[j]) * i0[j], xm0[j]);
                o1[j] = fmaf(racc[j][1], bf2f(g1[j]) * i1[j], xm1[j]);
            }
            float* po = outb + (size_t)c * HW_ + h0 * W_ + w0;
            *(f32x4*)po        = o0;
            *(f32x4*)(po + W_) = o1;
        }
    }
}

// ---------- K3: fused CP-reconstruct + softmax + conv3d gate ----------
// 4 barriers. Gate tiles [c][w] (SGP2); denominators broadcast via sinv LDS.
__global__ __launch_bounds__(1024)
void k_main(
    const float* __restrict__ x,
    const float* __restrict__ Wc, const float* __restrict__ acp,
    const float* __restrict__ Ww, const float* __restrict__ awp,
    const float* __restrict__ Wh, const float* __restrict__ ahp,
    const float* __restrict__ W3,
    const float* __restrict__ gapc, const float* __restrict__ gw,
    const float* __restrict__ gh,
    float* __restrict__ out)
{
    __shared__ __align__(16) char smem[SMEM_SZ];
    unsigned short* sg0   = (unsigned short*)(smem + OFF_SG0);
    unsigned short* scout = (unsigned short*)(smem + OFF_SCOUT);
    unsigned short* sg1   = scout;                          // alias, post-bar2
    unsigned short* swout = (unsigned short*)(smem + OFF_SWOUT);
    float* sred0 = (float*)(smem + OFF_SRED0);              // alias swout
    float* sred1 = (float*)(smem + OFF_SRED1);
    float* shout = (float*)(smem + OFF_SHOUT);
    float* sinv0 = (float*)(smem + OFF_SINV0);
    float* sinv1 = (float*)(smem + OFF_SINV1);

    // swizzled decode: blocks round-robin XCDs; each XCD owns 4 whole batches
    const int bid  = blockIdx.x;
    const int slot = bid >> 3;
    const int b    = (bid & 7) * 4 + slot / NHT;
    const int h0   = (slot % NHT) * 2;

    const int tid  = threadIdx.x;
    const int lane = tid & 63;
    const int wid  = tid >> 6;
    const int g    = lane >> 4;
    const int col  = lane & 15;
    const float ac = acp[0], aw = awp[0], ah = ahp[0];

    // ----- staging: one c (or w) per thread; factor rows from GAP results -----
    {   // scout: c = tid>>2 (0..255), r = (tid&3)*16 .. +15
        const float* gc = gapc + b * C_;
        const int c  = tid >> 2;
        const int rq = tid & 3;
        const float gm = (c >= 1)      ? gc[c - 1] : 0.f;
        const float g0 = gc[c];
        const float gp = (c < C_ - 1)  ? gc[c + 1] : 0.f;
        const float* wc = Wc + rq * 48;
        unsigned short* dst = &scout[c * CPH + rq * 16];
        #pragma unroll
        for (int i = 0; i < 16; i += 4) {
            f32x4 vv;
            #pragma unroll
            for (int k = 0; k < 4; ++k) {
                float v = wc[(i+k)*3+0] * gm + wc[(i+k)*3+1] * g0 + wc[(i+k)*3+2] * gp;
                vv[k] = (v >= 0.f) ? v : ac * v;
            }
            u32x2 pkd = { pkbf(vv[0], vv[1]), pkbf(vv[2], vv[3]) };
            *(u32x2*)&dst[i] = pkd;
        }
    }
    {   // swout: w = tid>>4 (0..63), r = (tid&15)*4 .. +3
        const float* gwb = gw + b * W_;
        const int w  = tid >> 4;
        const int rq = tid & 15;
        float gm = 0.f, g0 = 0.f, gp = 0.f;
        if (w < W_) {
            gm = (w >= 1)     ? gwb[w - 1] * (1.f / CH_) : 0.f;
            g0 = gwb[w] * (1.f / CH_);
            gp = (w < W_ - 1) ? gwb[w + 1] * (1.f / CH_) : 0.f;
        }
        const float* ww = Ww + rq * 12;
        f32x4 vv;
        #pragma unroll
        for (int k = 0; k < 4; ++k) {
            float v = ww[k*3+0] * gm + ww[k*3+1] * g0 + ww[k*3+2] * gp;
            vv[k] = (v >= 0.f) ? v : aw * v;
        }
        u32x2 pkd = { pkbf(vv[0], vv[1]), pkbf(vv[2], vv[3]) };
        *(u32x2*)&swout[w * CPH + rq * 4] = pkd;
    }
    if (tid < 2 * 64) {   // shout (f32)
        const float* ghb = gh + b * H_;
        const int hr = tid >> 6, r = tid & 63;
        const int h = h0 + hr;
        const float gm = (h >= 1)     ? ghb[h - 1] * (1.f / CH_) : 0.f;
        const float g0 = ghb[h] * (1.f / CH_);
        const float gp = (h < H_ - 1) ? ghb[h + 1] * (1.f / CH_) : 0.f;
        float v = Wh[r * 3 + 0] * gm + Wh[r * 3 + 1] * g0 + Wh[r * 3 + 2] * gp;
        shout[hr * CPH + r] = (v >= 0.f) ? v : ah * v;
    }
    __syncthreads();                                        // bar1

    const int cbase = wid * 16;
    const int crow  = cbase + col;
    const int cr    = cbase + g * 4;

    // ----- MFMA both rows fused: one fragment read feeds 2 MFMAs -----
    f32x4 acc[8];                   // 0-3: row0 tiles t=0..3; 4-7: row1
    #pragma unroll
    for (int t = 0; t < 8; ++t) acc[t] = (f32x4){0,0,0,0};
    #pragma unroll
    for (int kc = 0; kc < 2; ++kc) {
        const int r0 = kc * 32 + g * 4;
        f32x4 ca = bf2f4(*(ush4*)&scout[crow * CPH + r0]);
        f32x4 cb = bf2f4(*(ush4*)&scout[crow * CPH + r0 + 16]);
        f32x4 ha0 = *(f32x4*)&shout[0 * CPH + r0];
        f32x4 hb0 = *(f32x4*)&shout[0 * CPH + r0 + 16];
        f32x4 ha1 = *(f32x4*)&shout[1 * CPH + r0];
        f32x4 hb1 = *(f32x4*)&shout[1 * CPH + r0 + 16];
        s16x8 af0 = pack8(ca * ha0, cb * hb0);
        s16x8 af1 = pack8(ca * ha1, cb * hb1);
        #pragma unroll
        for (int t = 0; t < 4; ++t) {
            s16x8 bfr = cat8(*(ush4*)&swout[(t*16+col)*CPH + r0],
                             *(ush4*)&swout[(t*16+col)*CPH + r0 + 16]);
            acc[t]     = __builtin_amdgcn_mfma_f32_16x16x32_bf16(af0, bfr, acc[t],     0, 0, 0);
            acc[4 + t] = __builtin_amdgcn_mfma_f32_16x16x32_bf16(af1, bfr, acc[4 + t], 0, 0, 0);
        }
    }
    // exp + wave-partial sums (f32 butterfly); write row0 e-tile to sg0 [c][w]
    float s0p, s1p;
    {
        float st0[4], st1[4];
        #pragma unroll
        for (int t = 0; t < 4; ++t) {
            #pragma unroll
            for (int j = 0; j < 4; ++j) { acc[t][j] = __expf(acc[t][j]); acc[4+t][j] = __expf(acc[4+t][j]); }
            float s0 = acc[t][0] + acc[t][1] + acc[t][2] + acc[t][3];
            float s1 = acc[4+t][0] + acc[4+t][1] + acc[4+t][2] + acc[4+t][3];
            s0 += __shfl_xor(s0, 16, 64);  s0 += __shfl_xor(s0, 32, 64);
            s1 += __shfl_xor(s1, 16, 64);  s1 += __shfl_xor(s1, 32, 64);
            st0[t] = s0; st1[t] = s1;
        }
        s0p = (g == 0) ? st0[0] : (g == 1) ? st0[1] : (g == 2) ? st0[2] : st0[3];
        s1p = (g == 0) ? st1[0] : (g == 1) ? st1[1] : (g == 2) ? st1[2] : st1[3];
        #pragma unroll
        for (int t = 0; t < 4; ++t) {
            const int w = t * 16 + col;
            if (w < W_) {
                sg0[(cr + 0) * SGP2 + w] = f2bf(acc[t][0]);
                sg0[(cr + 1) * SGP2 + w] = f2bf(acc[t][1]);
                sg0[(cr + 2) * SGP2 + w] = f2bf(acc[t][2]);
                sg0[(cr + 3) * SGP2 + w] = f2bf(acc[t][3]);
            }
        }
    }
    __syncthreads();                                        // bar2: scout/swout reads done
    {
        #pragma unroll
        for (int t = 0; t < 4; ++t) {
            const int w = t * 16 + col;
            if (w < W_) {
                sg1[(cr + 0) * SGP2 + w] = f2bf(acc[4+t][0]);
                sg1[(cr + 1) * SGP2 + w] = f2bf(acc[4+t][1]);
                sg1[(cr + 2) * SGP2 + w] = f2bf(acc[4+t][2]);
                sg1[(cr + 3) * SGP2 + w] = f2bf(acc[4+t][3]);
            }
        }
        sred0[wid * 64 + lane] = s0p;
        sred1[wid * 64 + lane] = s1p;
    }
    __syncthreads();                                        // bar3

    // denominators: wave 0 sums partials and broadcasts 1/T via sinv
    if (wid == 0 && lane < W_) {
        float T0 = 0.f, T1 = 0.f;
        #pragma unroll
        for (int t = 0; t < 16; ++t) {
            T0 += sred0[t * 64 + lane];
            T1 += sred1[t * 64 + lane];
        }
        sinv0[lane] = 1.f / T0;
        sinv1[lane] = 1.f / T1;
    }
    __syncthreads();                                        // bar4

    const float* xb = x + (size_t)b * C_ * HW_;
    float* outb = out + (size_t)b * C_ * HW_;
    if (h0 == 0 || h0 == H_ - 2)
        conv_store<true >(xb, W3, sg0, sg1, sinv0, sinv1, h0, cbase, lane, outb);
    else
        conv_store<false>(xb, W3, sg0, sg1, sinv0, sinv1, h0, cbase, lane, outb);
}

extern "C" void kernel_launch(void* const* d_in, const int* in_sizes, int n_in,
                              void* d_out, int out_size, void* d_ws, size_t ws_size,
                              hipStream_t stream) {
    const float* x  = (const float*)d_in[0];
    const float* Wc = (const float*)d_in[1];
    const float* ac = (const float*)d_in[2];
    const float* Ww = (const float*)d_in[3];
    const float* aw = (const float*)d_in[4];
    const float* Wh = (const float*)d_in[5];
    const float* ah = (const float*)d_in[6];
    const float* W3 = (const float*)d_in[7];
    float* out  = (float*)d_out;
    float* gapc = (float*)d_ws;                 // B*C
    float* gwp  = gapc + B_ * C_;               // B*W (raw sums)
    float* ghp  = gwp + B_ * W_;                // B*H (raw sums)

    (void)hipMemsetAsync(gwp, 0, (size_t)(B_ * W_ + B_ * H_) * sizeof(float), stream);
    k_reduce<<<dim3(B_ * (C_ / CGRP)), dim3(832), 0, stream>>>(x, gapc, gwp, ghp);
    k_main<<<dim3(B_ * NHT), dim3(1024), 0, stream>>>(
        x, Wc, ac, Ww, aw, Wh, ah, W3, gapc, gwp, ghp, out);
}

// Round 18
// 108.513 us; speedup vs baseline: 1.0332x; 1.0332x over previous
//
#include <hip/hip_runtime.h>
#include <hip/hip_bf16.h>

typedef float f32x4 __attribute__((ext_vector_type(4)));
typedef float f32x2 __attribute__((ext_vector_type(2)));
typedef short s16x8 __attribute__((ext_vector_type(8)));
typedef unsigned short ush4 __attribute__((ext_vector_type(4)));
typedef unsigned u32x4 __attribute__((ext_vector_type(4)));
typedef unsigned u32x2 __attribute__((ext_vector_type(2)));

#define B_ 32
#define C_ 256
#define H_ 56
#define W_ 56
#define HW_ (H_*W_)     // 3136
#define CH_ 14336       // C_*H_ == C_*W_
#define NHT 28          // H_/2 row-tiles per batch
#define CPH 68          // ushort stride scout/swout (8B-aligned b64 frag loads)
#define SGPT 260        // ushort stride for TRANSPOSED gate tiles [w][c] (520B/row)
#define CGRP 16         // channels per k_reduce block

// LDS layout (73184 B -> 2 blocks/CU). sg1T aliases scout; sred0/1 alias swout.
#define OFF_SG0T  0          // 29120 B (56*260*2)
#define OFF_SCOUT 29120      // 34816 B (256*68*2)  [∪ sg1T 29120]
#define OFF_SWOUT 63936      //  8704 B (64*68*2)   [∪ sred0(4096)+sred1(4096)]
#define OFF_SRED0 63936
#define OFF_SRED1 68032
#define OFF_SHOUT 72640      //   544 B (2*68*4)
#define SMEM_SZ   73184

// ---------- helpers ----------
__device__ __forceinline__ unsigned short f2bf(float f) {
    unsigned u = __float_as_uint(f);
    u += 0x7fffu + ((u >> 16) & 1u);     // round-to-nearest-even
    return (unsigned short)(u >> 16);
}
__device__ __forceinline__ float bf2f(unsigned short u) {
    return __uint_as_float((unsigned)u << 16);
}
__device__ __forceinline__ f32x4 bf2f4(ush4 u) {
    f32x4 r; r[0] = bf2f(u[0]); r[1] = bf2f(u[1]); r[2] = bf2f(u[2]); r[3] = bf2f(u[3]);
    return r;
}
// pair-pack via intrinsic so the compiler emits v_cvt_pk_bf16_f32 (m240: do
// NOT hand-write the asm form). low word = first operand.
__device__ __forceinline__ unsigned pkbf(float lo, float hi) {
    __hip_bfloat162 h = __float22bfloat162_rn(make_float2(lo, hi));
    unsigned r;
    __builtin_memcpy(&r, &h, 4);
    return r;
}
__device__ __forceinline__ s16x8 pack8(f32x4 a, f32x4 b) {
    u32x4 t = { pkbf(a[0], a[1]), pkbf(a[2], a[3]), pkbf(b[0], b[1]), pkbf(b[2], b[3]) };
    s16x8 r;
    __builtin_memcpy(&r, &t, 16);
    return r;
}
__device__ __forceinline__ s16x8 cat8(ush4 a, ush4 b) {
    s16x8 r;
    r[0] = (short)a[0]; r[1] = (short)a[1]; r[2] = (short)a[2]; r[3] = (short)a[3];
    r[4] = (short)b[0]; r[5] = (short)b[1]; r[6] = (short)b[2]; r[7] = (short)b[3];
    return r;
}
__device__ __forceinline__ float dpp_shr1(float v) {   // lane i <- v[i-1]; lane0 <- 0 (bound_ctrl)
    return __int_as_float(__builtin_amdgcn_mov_dpp(__float_as_int(v), 0x138, 0xf, 0xf, true));
}
__device__ __forceinline__ float dpp_shl1(float v) {   // lane i <- v[i+1]; lane63 <- 0
    return __int_as_float(__builtin_amdgcn_mov_dpp(__float_as_int(v), 0x130, 0xf, 0xf, true));
}

// ---------- K1: GAP reductions (hierarchical; 1 global atomic per value per block) ----------
__global__ __launch_bounds__(832) void k_reduce(const float* __restrict__ x,
                                                float* __restrict__ gapc,
                                                float* __restrict__ gw,
                                                float* __restrict__ gh) {
    __shared__ float chanpart[13 * CGRP];
    __shared__ float rowsum[H_];
    __shared__ float colsum[W_];
    const int bid = blockIdx.x;
    const int b  = bid >> 4;
    const int c0 = (bid & 15) * CGRP;
    const int tid = threadIdx.x;
    const int lane = tid & 63, wid = tid >> 6;
    if (tid < H_) rowsum[tid] = 0.f;
    else if (tid >= 64 && tid < 64 + W_) colsum[tid - 64] = 0.f;
    __syncthreads();

    const bool act = tid < 784;
    const int j = act ? tid : 0;
    const float* px = x + (size_t)(b * C_ + c0) * HW_ + j * 4;
    f32x4 posacc = {0, 0, 0, 0};
    #pragma unroll 4
    for (int c = 0; c < CGRP; ++c) {
        f32x4 v = {0, 0, 0, 0};
        if (act) v = *(const f32x4*)(px + (size_t)c * HW_);
        posacc += v;
        float s = v[0] + v[1] + v[2] + v[3];
        #pragma unroll
        for (int d = 1; d < 64; d <<= 1) s += __shfl_xor(s, d, 64);
        if (lane == 0) chanpart[wid * CGRP + c] = s;
    }
    if (act) {
        const int h = j / 14, w4 = j % 14;
        atomicAdd(&rowsum[h], posacc[0] + posacc[1] + posacc[2] + posacc[3]);
        atomicAdd(&colsum[w4 * 4 + 0], posacc[0]);
        atomicAdd(&colsum[w4 * 4 + 1], posacc[1]);
        atomicAdd(&colsum[w4 * 4 + 2], posacc[2]);
        atomicAdd(&colsum[w4 * 4 + 3], posacc[3]);
    }
    __syncthreads();
    if (tid < CGRP) {
        float t = 0.f;
        #pragma unroll
        for (int w = 0; w < 13; ++w) t += chanpart[w * CGRP + tid];
        gapc[b * C_ + c0 + tid] = t * (1.f / HW_);
    } else if (tid >= 64 && tid < 64 + H_) {
        atomicAdd(&gh[b * H_ + (tid - 64)], rowsum[tid - 64]);
    } else if (tid >= 128 && tid < 128 + W_) {
        atomicAdd(&gw[b * W_ + (tid - 128)], colsum[tid - 128]);
    }
}

// ---------- conv3d + gated store (templated on h-boundary) ----------
// Round-16 proven form: lane = w, branch-free clamped loads, channel-tap
// sharing via kl-loop, dual-row f32x2 packed accumulators (v_pk_fma_f32),
// DPP bound_ctrl provides lane-0 zero; v[56..63]==0 provides right pad.
template<bool EDGE>
__device__ __forceinline__ void conv_store(
    const float* __restrict__ xb, const float* __restrict__ W3,
    const unsigned short* sg0, const unsigned short* sg1,
    float invS0, float invS1, int h0, int cbase, int lane, int lw,
    float* __restrict__ outb)
{
    #pragma unroll 1
    for (int q = 0; q < 4; ++q) {
        const int c4 = cbase + q * 4;
        f32x2 res01[4] = {{0,0},{0,0},{0,0},{0,0}};
        float xm0[4], xm1[4];
        #pragma unroll
        for (int ci = 0; ci < 6; ++ci) {
            const int cc  = c4 - 1 + ci;
            const bool cok = (cc >= 0) && (cc < C_);
            const int ccl = cc < 0 ? 0 : (cc > C_ - 1 ? C_ - 1 : cc);
            const float* pc = xb + (size_t)ccl * HW_ + lw;
            #pragma unroll
            for (int jr = 0; jr < 4; ++jr) {
                float v;
                bool keep = cok && (lane < W_);
                if (EDGE) {
                    const int hh  = h0 - 1 + jr;
                    keep = keep && (hh >= 0) && (hh < H_);
                    const int hcl = hh < 0 ? 0 : (hh > H_ - 1 ? H_ - 1 : hh);
                    v = pc[hcl * W_];
                } else {
                    v = pc[(h0 - 1 + jr) * W_];
                }
                v = keep ? v : 0.f;
                // residual capture: center channel (cc==c4+ci-1), rows h0/h0+1
                if (ci >= 1 && ci <= 4) {
                    if (jr == 1) xm0[ci - 1] = v;
                    if (jr == 2) xm1[ci - 1] = v;
                }
                const float vl = dpp_shr1(v);           // lane0 -> 0 (bound_ctrl)
                const float vr = dpp_shl1(v);           // lane55 -> v[56]==0
                #pragma unroll
                for (int kl = 0; kl < 4; ++kl) {
                    const int dz = ci - kl;             // weight channel offset
                    if (dz >= 0 && dz <= 2) {
                        if (jr >= 1 && jr <= 2) {
                            // packed: row0 dy=jr, row1 dy=jr-1
                            const int wi0 = (dz * 3 + jr) * 3;
                            const int wi1 = (dz * 3 + jr - 1) * 3;
                            const f32x2 vl2 = {vl, vl}, v2 = {v, v}, vr2 = {vr, vr};
                            const f32x2 w0 = {W3[wi0+0], W3[wi1+0]};
                            const f32x2 w1 = {W3[wi0+1], W3[wi1+1]};
                            const f32x2 w2 = {W3[wi0+2], W3[wi1+2]};
                            res01[kl] = __builtin_elementwise_fma(w0, vl2,
                                        __builtin_elementwise_fma(w1, v2,
                                        __builtin_elementwise_fma(w2, vr2, res01[kl])));
                        } else if (jr == 0) {           // row0 only, dy=0
                            const int wi = (dz * 3 + 0) * 3;
                            res01[kl][0] = fmaf(W3[wi], vl, fmaf(W3[wi+1], v, fmaf(W3[wi+2], vr, res01[kl][0])));
                        } else {                        // jr==3: row1 only, dy=2
                            const int wi = (dz * 3 + 2) * 3;
                            res01[kl][1] = fmaf(W3[wi], vl, fmaf(W3[wi+1], v, fmaf(W3[wi+2], vr, res01[kl][1])));
                        }
                    }
                }
            }
        }
        if (lane < W_) {
            const ush4 q0 = *(const ush4*)&sg0[lane * SGPT + c4];   // 4 gates, one b64
            const ush4 q1 = *(const ush4*)&sg1[lane * SGPT + c4];
            #pragma unroll
            for (int kk = 0; kk < 4; ++kk) {
                const int c = c4 + kk;
                const size_t xi = ((size_t)c * H_ + h0) * W_ + lane;
                outb[xi]      = fmaf(res01[kk][0], bf2f(q0[kk]) * invS0, xm0[kk]);
                outb[xi + W_] = fmaf(res01[kk][1], bf2f(q1[kk]) * invS1, xm1[kk]);
            }
        }
    }
}

// ---------- K3: fused CP-reconstruct + softmax + conv3d gate ----------
__global__ __launch_bounds__(1024)
void k_main(
    const float* __restrict__ x,
    const float* __restrict__ Wc, const float* __restrict__ acp,
    const float* __restrict__ Ww, const float* __restrict__ awp,
    const float* __restrict__ Wh, const float* __restrict__ ahp,
    const float* __restrict__ W3,
    const float* __restrict__ gapc, const float* __restrict__ gw,
    const float* __restrict__ gh,
    float* __restrict__ out)
{
    __shared__ __align__(16) char smem[SMEM_SZ];
    unsigned short* sg0   = (unsigned short*)(smem + OFF_SG0T);
    unsigned short* scout = (unsigned short*)(smem + OFF_SCOUT);
    unsigned short* sg1   = scout;                          // alias, post-bar2
    unsigned short* swout = (unsigned short*)(smem + OFF_SWOUT);
    float* sred0 = (float*)(smem + OFF_SRED0);              // alias swout
    float* sred1 = (float*)(smem + OFF_SRED1);
    float* shout = (float*)(smem + OFF_SHOUT);

    // swizzled decode: blocks round-robin XCDs; each XCD owns 4 whole batches
    const int bid  = blockIdx.x;
    const int slot = bid >> 3;
    const int b    = (bid & 7) * 4 + slot / NHT;
    const int h0   = (slot % NHT) * 2;

    const int tid  = threadIdx.x;
    const int lane = tid & 63;
    const int wid  = tid >> 6;
    const int g    = lane >> 4;
    const int col  = lane & 15;
    const int lw   = (lane < W_) ? lane : (W_ - 1);
    const float ac = acp[0], aw = awp[0], ah = ahp[0];

    // ----- staging: one c (or w) per thread; factor rows from GAP results -----
    {   // scout: c = tid>>2 (0..255), r = (tid&3)*16 .. +15
        const float* gc = gapc + b * C_;
        const int c  = tid >> 2;
        const int rq = tid & 3;
        const float gm = (c >= 1)      ? gc[c - 1] : 0.f;
        const float g0 = gc[c];
        const float gp = (c < C_ - 1)  ? gc[c + 1] : 0.f;
        const float* wc = Wc + rq * 48;
        unsigned short* dst = &scout[c * CPH + rq * 16];
        #pragma unroll
        for (int i = 0; i < 16; i += 4) {
            f32x4 vv;
            #pragma unroll
            for (int k = 0; k < 4; ++k) {
                float v = wc[(i+k)*3+0] * gm + wc[(i+k)*3+1] * g0 + wc[(i+k)*3+2] * gp;
                vv[k] = (v >= 0.f) ? v : ac * v;
            }
            u32x2 pkd = { pkbf(vv[0], vv[1]), pkbf(vv[2], vv[3]) };
            *(u32x2*)&dst[i] = pkd;
        }
    }
    {   // swout: w = tid>>4 (0..63), r = (tid&15)*4 .. +3
        const float* gwb = gw + b * W_;
        const int w  = tid >> 4;
        const int rq = tid & 15;
        float gm = 0.f, g0 = 0.f, gp = 0.f;
        if (w < W_) {
            gm = (w >= 1)     ? gwb[w - 1] * (1.f / CH_) : 0.f;
            g0 = gwb[w] * (1.f / CH_);
            gp = (w < W_ - 1) ? gwb[w + 1] * (1.f / CH_) : 0.f;
        }
        const float* ww = Ww + rq * 12;
        f32x4 vv;
        #pragma unroll
        for (int k = 0; k < 4; ++k) {
            float v = ww[k*3+0] * gm + ww[k*3+1] * g0 + ww[k*3+2] * gp;
            vv[k] = (v >= 0.f) ? v : aw * v;
        }
        u32x2 pkd = { pkbf(vv[0], vv[1]), pkbf(vv[2], vv[3]) };
        *(u32x2*)&swout[w * CPH + rq * 4] = pkd;
    }
    if (tid < 2 * 64) {   // shout (f32)
        const float* ghb = gh + b * H_;
        const int hr = tid >> 6, r = tid & 63;
        const int h = h0 + hr;
        const float gm = (h >= 1)     ? ghb[h - 1] * (1.f / CH_) : 0.f;
        const float g0 = ghb[h] * (1.f / CH_);
        const float gp = (h < H_ - 1) ? ghb[h + 1] * (1.f / CH_) : 0.f;
        float v = Wh[r * 3 + 0] * gm + Wh[r * 3 + 1] * g0 + Wh[r * 3 + 2] * gp;
        shout[hr * CPH + r] = (v >= 0.f) ? v : ah * v;
    }
    __syncthreads();                                        // bar1

    const int cbase = wid * 16;
    const int crow  = cbase + col;
    const int cr    = cbase + g * 4;

    // ----- MFMA both rows fused: one fragment read feeds 2 MFMAs -----
    f32x4 acc[8];                   // 0-3: row0 tiles t=0..3; 4-7: row1
    #pragma unroll
    for (int t = 0; t < 8; ++t) acc[t] = (f32x4){0,0,0,0};
    #pragma unroll
    for (int kc = 0; kc < 2; ++kc) {
        const int r0 = kc * 32 + g * 4;
        f32x4 ca = bf2f4(*(ush4*)&scout[crow * CPH + r0]);
        f32x4 cb = bf2f4(*(ush4*)&scout[crow * CPH + r0 + 16]);
        f32x4 ha0 = *(f32x4*)&shout[0 * CPH + r0];
        f32x4 hb0 = *(f32x4*)&shout[0 * CPH + r0 + 16];
        f32x4 ha1 = *(f32x4*)&shout[1 * CPH + r0];
        f32x4 hb1 = *(f32x4*)&shout[1 * CPH + r0 + 16];
        s16x8 af0 = pack8(ca * ha0, cb * hb0);
        s16x8 af1 = pack8(ca * ha1, cb * hb1);
        #pragma unroll
        for (int t = 0; t < 4; ++t) {
            s16x8 bfr = cat8(*(ush4*)&swout[(t*16+col)*CPH + r0],
                             *(ush4*)&swout[(t*16+col)*CPH + r0 + 16]);
            acc[t]     = __builtin_amdgcn_mfma_f32_16x16x32_bf16(af0, bfr, acc[t],     0, 0, 0);
            acc[4 + t] = __builtin_amdgcn_mfma_f32_16x16x32_bf16(af1, bfr, acc[4 + t], 0, 0, 0);
        }
    }
    // exp + wave-partial sums (f32 butterfly); write row0 e-tile to sg0
    float s0p, s1p;
    {
        float st0[4], st1[4];
        #pragma unroll
        for (int t = 0; t < 4; ++t) {
            #pragma unroll
            for (int j = 0; j < 4; ++j) { acc[t][j] = __expf(acc[t][j]); acc[4+t][j] = __expf(acc[4+t][j]); }
            float s0 = acc[t][0] + acc[t][1] + acc[t][2] + acc[t][3];
            float s1 = acc[4+t][0] + acc[4+t][1] + acc[4+t][2] + acc[4+t][3];
            s0 += __shfl_xor(s0, 16, 64);  s0 += __shfl_xor(s0, 32, 64);
            s1 += __shfl_xor(s1, 16, 64);  s1 += __shfl_xor(s1, 32, 64);
            st0[t] = s0; st1[t] = s1;
        }
        s0p = (g == 0) ? st0[0] : (g == 1) ? st0[1] : (g == 2) ? st0[2] : st0[3];
        s1p = (g == 0) ? st1[0] : (g == 1) ? st1[1] : (g == 2) ? st1[2] : st1[3];
        #pragma unroll
        for (int t = 0; t < 4; ++t) {
            const int w = t * 16 + col;
            if (w < W_) {
                u32x2 pkd = { pkbf(acc[t][0], acc[t][1]), pkbf(acc[t][2], acc[t][3]) };
                *(u32x2*)&sg0[w * SGPT + cr] = pkd;
            }
        }
    }
    __syncthreads();                                        // bar2: scout/swout reads done
    {
        #pragma unroll
        for (int t = 0; t < 4; ++t) {
            const int w = t * 16 + col;
            if (w < W_) {
                u32x2 pkd = { pkbf(acc[4+t][0], acc[4+t][1]), pkbf(acc[4+t][2], acc[4+t][3]) };
                *(u32x2*)&sg1[w * SGPT + cr] = pkd;
            }
        }
        sred0[wid * 64 + lane] = s0p;
        sred1[wid * 64 + lane] = s1p;
    }
    __syncthreads();                                        // bar3

    float invS0, invS1;
    {
        float T0 = 0.f, T1 = 0.f;
        #pragma unroll
        for (int t = 0; t < 16; ++t) {
            T0 += sred0[t * 64 + lane];
            T1 += sred1[t * 64 + lane];
        }
        invS0 = 1.f / T0;
        invS1 = 1.f / T1;
    }

    const float* xb = x + (size_t)b * C_ * HW_;
    float* outb = out + (size_t)b * C_ * HW_;
    if (h0 == 0 || h0 == H_ - 2)
        conv_store<true >(xb, W3, sg0, sg1, invS0, invS1, h0, cbase, lane, lw, outb);
    else
        conv_store<false>(xb, W3, sg0, sg1, invS0, invS1, h0, cbase, lane, lw, outb);
}

extern "C" void kernel_launch(void* const* d_in, const int* in_sizes, int n_in,
                              void* d_out, int out_size, void* d_ws, size_t ws_size,
                              hipStream_t stream) {
    const float* x  = (const float*)d_in[0];
    const float* Wc = (const float*)d_in[1];
    const float* ac = (const float*)d_in[2];
    const float* Ww = (const float*)d_in[3];
    const float* aw = (const float*)d_in[4];
    const float* Wh = (const float*)d_in[5];
    const float* ah = (const float*)d_in[6];
    const float* W3 = (const float*)d_in[7];
    float* out  = (float*)d_out;
    float* gapc = (float*)d_ws;                 // B*C
    float* gwp  = gapc + B_ * C_;               // B*W (raw sums)
    float* ghp  = gwp + B_ * W_;                // B*H (raw sums)

    (void)hipMemsetAsync(gwp, 0, (size_t)(B_ * W_ + B_ * H_) * sizeof(float), stream);
    k_reduce<<<dim3(B_ * (C_ / CGRP)), dim3(832), 0, stream>>>(x, gapc, gwp, ghp);
    k_main<<<dim3(B_ * NHT), dim3(1024), 0, stream>>>(
        x, Wc, ac, Ww, aw, Wh, ah, W3, gapc, gwp, ghp, out);
}

// Round 20
// 106.822 us; speedup vs baseline: 1.0496x; 1.0158x over previous
//
#include <hip/hip_runtime.h>
#include <hip/hip_bf16.h>

typedef float f32x4 __attribute__((ext_vector_type(4)));
typedef float f32x2 __attribute__((ext_vector_type(2)));
typedef short s16x8 __attribute__((ext_vector_type(8)));
typedef unsigned short ush4 __attribute__((ext_vector_type(4)));
typedef unsigned u32x4 __attribute__((ext_vector_type(4)));
typedef unsigned u32x2 __attribute__((ext_vector_type(2)));

#define B_ 32
#define C_ 256
#define H_ 56
#define W_ 56
#define HW_ (H_*W_)     // 3136
#define CH_ 14336       // C_*H_ == C_*W_
#define NHT 28          // H_/2 row-tiles per batch
#define CPH 68          // ushort stride scout/swout (8B-aligned b64 frag loads)
#define SGPT 260        // ushort stride for TRANSPOSED gate tiles [w][c] (520B/row)
#define CGRP 16         // channels per k_reduce block

// LDS layout (73184 B -> 2 blocks/CU). sg1T aliases scout; sred0/1 alias swout.
#define OFF_SG0T  0          // 29120 B (56*260*2)
#define OFF_SCOUT 29120      // 34816 B (256*68*2)  [∪ sg1T 29120]
#define OFF_SWOUT 63936      //  8704 B (64*68*2)   [∪ sred0(4096)+sred1(4096)]
#define OFF_SRED0 63936
#define OFF_SRED1 68032
#define OFF_SHOUT 72640      //   544 B (2*68*4)
#define SMEM_SZ   73184

// ---------- helpers ----------
__device__ __forceinline__ unsigned short f2bf(float f) {
    unsigned u = __float_as_uint(f);
    u += 0x7fffu + ((u >> 16) & 1u);     // round-to-nearest-even
    return (unsigned short)(u >> 16);
}
__device__ __forceinline__ float bf2f(unsigned short u) {
    return __uint_as_float((unsigned)u << 16);
}
__device__ __forceinline__ f32x4 bf2f4(ush4 u) {
    f32x4 r; r[0] = bf2f(u[0]); r[1] = bf2f(u[1]); r[2] = bf2f(u[2]); r[3] = bf2f(u[3]);
    return r;
}
// pair-pack via intrinsic so the compiler emits v_cvt_pk_bf16_f32 (m240: do
// NOT hand-write the asm form). low word = first operand.
__device__ __forceinline__ unsigned pkbf(float lo, float hi) {
    __hip_bfloat162 h = __float22bfloat162_rn(make_float2(lo, hi));
    unsigned r;
    __builtin_memcpy(&r, &h, 4);
    return r;
}
__device__ __forceinline__ s16x8 pack8(f32x4 a, f32x4 b) {
    u32x4 t = { pkbf(a[0], a[1]), pkbf(a[2], a[3]), pkbf(b[0], b[1]), pkbf(b[2], b[3]) };
    s16x8 r;
    __builtin_memcpy(&r, &t, 16);
    return r;
}
__device__ __forceinline__ s16x8 cat8(ush4 a, ush4 b) {
    s16x8 r;
    r[0] = (short)a[0]; r[1] = (short)a[1]; r[2] = (short)a[2]; r[3] = (short)a[3];
    r[4] = (short)b[0]; r[5] = (short)b[1]; r[6] = (short)b[2]; r[7] = (short)b[3];
    return r;
}
__device__ __forceinline__ float dpp_shr1(float v) {   // lane i <- v[i-1]; lane0 <- 0 (bound_ctrl)
    return __int_as_float(__builtin_amdgcn_mov_dpp(__float_as_int(v), 0x138, 0xf, 0xf, true));
}
__device__ __forceinline__ float dpp_shl1(float v) {   // lane i <- v[i+1]; lane63 <- 0
    return __int_as_float(__builtin_amdgcn_mov_dpp(__float_as_int(v), 0x130, 0xf, 0xf, true));
}
// DPP 64-lane sum (rocPRIM gfx9 idiom): 6 VALU adds, zero LDS-pipe traffic.
// DPP ctrl must be a LITERAL -> hand-unrolled. Result valid in lane 63.
__device__ __forceinline__ float dpp_reduce_add(float s) {
    s += __int_as_float(__builtin_amdgcn_mov_dpp(__float_as_int(s), 0x111, 0xf, 0xf, true)); // row_shr:1
    s += __int_as_float(__builtin_amdgcn_mov_dpp(__float_as_int(s), 0x112, 0xf, 0xf, true)); // row_shr:2
    s += __int_as_float(__builtin_amdgcn_mov_dpp(__float_as_int(s), 0x114, 0xf, 0xf, true)); // row_shr:4
    s += __int_as_float(__builtin_amdgcn_mov_dpp(__float_as_int(s), 0x118, 0xf, 0xf, true)); // row_shr:8
    s += __int_as_float(__builtin_amdgcn_mov_dpp(__float_as_int(s), 0x142, 0xa, 0xf, true)); // row_bcast:15
    s += __int_as_float(__builtin_amdgcn_mov_dpp(__float_as_int(s), 0x143, 0xc, 0xf, true)); // row_bcast:31
    return s;       // lane 63 holds the full 64-lane sum
}

// ---------- K1: GAP reductions (hierarchical; 1 global atomic per value per block) ----------
__global__ __launch_bounds__(832) void k_reduce(const float* __restrict__ x,
                                                float* __restrict__ gapc,
                                                float* __restrict__ gw,
                                                float* __restrict__ gh) {
    __shared__ float chanpart[13 * CGRP];
    __shared__ float rowsum[H_];
    __shared__ float colsum[W_];
    const int bid = blockIdx.x;
    const int b  = bid >> 4;
    const int c0 = (bid & 15) * CGRP;
    const int tid = threadIdx.x;
    const int lane = tid & 63, wid = tid >> 6;
    if (tid < H_) rowsum[tid] = 0.f;
    else if (tid >= 64 && tid < 64 + W_) colsum[tid - 64] = 0.f;
    __syncthreads();

    const bool act = tid < 784;
    const int j = act ? tid : 0;
    const float* px = x + (size_t)(b * C_ + c0) * HW_ + j * 4;
    f32x4 posacc = {0, 0, 0, 0};
    #pragma unroll 4
    for (int c = 0; c < CGRP; ++c) {
        f32x4 v = {0, 0, 0, 0};
        if (act) v = *(const f32x4*)(px + (size_t)c * HW_);
        posacc += v;
        float s = dpp_reduce_add(v[0] + v[1] + v[2] + v[3]);   // 6 VALU, no LDS
        if (lane == 63) chanpart[wid * CGRP + c] = s;
    }
    if (act) {
        const int h = j / 14, w4 = j % 14;
        atomicAdd(&rowsum[h], posacc[0] + posacc[1] + posacc[2] + posacc[3]);
        atomicAdd(&colsum[w4 * 4 + 0], posacc[0]);
        atomicAdd(&colsum[w4 * 4 + 1], posacc[1]);
        atomicAdd(&colsum[w4 * 4 + 2], posacc[2]);
        atomicAdd(&colsum[w4 * 4 + 3], posacc[3]);
    }
    __syncthreads();
    if (tid < CGRP) {
        float t = 0.f;
        #pragma unroll
        for (int w = 0; w < 13; ++w) t += chanpart[w * CGRP + tid];
        gapc[b * C_ + c0 + tid] = t * (1.f / HW_);
    } else if (tid >= 64 && tid < 64 + H_) {
        atomicAdd(&gh[b * H_ + (tid - 64)], rowsum[tid - 64]);
    } else if (tid >= 128 && tid < 128 + W_) {
        atomicAdd(&gw[b * W_ + (tid - 128)], colsum[tid - 128]);
    }
}

// ---------- conv3d + gated store (templated on h-boundary) ----------
// Round-16 proven form: lane = w, branch-free clamped loads, channel-tap
// sharing via kl-loop, dual-row f32x2 packed accumulators (v_pk_fma_f32),
// DPP bound_ctrl provides lane-0 zero; v[56..63]==0 provides right pad.
template<bool EDGE>
__device__ __forceinline__ void conv_store(
    const float* __restrict__ xb, const float* __restrict__ W3,
    const unsigned short* sg0, const unsigned short* sg1,
    float invS0, float invS1, int h0, int cbase, int lane, int lw,
    float* __restrict__ outb)
{
    #pragma unroll 1
    for (int q = 0; q < 4; ++q) {
        const int c4 = cbase + q * 4;
        f32x2 res01[4] = {{0,0},{0,0},{0,0},{0,0}};
        float xm0[4], xm1[4];
        #pragma unroll
        for (int ci = 0; ci < 6; ++ci) {
            const int cc  = c4 - 1 + ci;
            const bool cok = (cc >= 0) && (cc < C_);
            const int ccl = cc < 0 ? 0 : (cc > C_ - 1 ? C_ - 1 : cc);
            const float* pc = xb + (size_t)ccl * HW_ + lw;
            #pragma unroll
            for (int jr = 0; jr < 4; ++jr) {
                float v;
                bool keep = cok && (lane < W_);
                if (EDGE) {
                    const int hh  = h0 - 1 + jr;
                    keep = keep && (hh >= 0) && (hh < H_);
                    const int hcl = hh < 0 ? 0 : (hh > H_ - 1 ? H_ - 1 : hh);
                    v = pc[hcl * W_];
                } else {
                    v = pc[(h0 - 1 + jr) * W_];
                }
                v = keep ? v : 0.f;
                // residual capture: center channel (cc==c4+ci-1), rows h0/h0+1
                if (ci >= 1 && ci <= 4) {
                    if (jr == 1) xm0[ci - 1] = v;
                    if (jr == 2) xm1[ci - 1] = v;
                }
                const float vl = dpp_shr1(v);           // lane0 -> 0 (bound_ctrl)
                const float vr = dpp_shl1(v);           // lane55 -> v[56]==0
                #pragma unroll
                for (int kl = 0; kl < 4; ++kl) {
                    const int dz = ci - kl;             // weight channel offset
                    if (dz >= 0 && dz <= 2) {
                        if (jr >= 1 && jr <= 2) {
                            // packed: row0 dy=jr, row1 dy=jr-1
                            const int wi0 = (dz * 3 + jr) * 3;
                            const int wi1 = (dz * 3 + jr - 1) * 3;
                            const f32x2 vl2 = {vl, vl}, v2 = {v, v}, vr2 = {vr, vr};
                            const f32x2 w0 = {W3[wi0+0], W3[wi1+0]};
                            const f32x2 w1 = {W3[wi0+1], W3[wi1+1]};
                            const f32x2 w2 = {W3[wi0+2], W3[wi1+2]};
                            res01[kl] = __builtin_elementwise_fma(w0, vl2,
                                        __builtin_elementwise_fma(w1, v2,
                                        __builtin_elementwise_fma(w2, vr2, res01[kl])));
                        } else if (jr == 0) {           // row0 only, dy=0
                            const int wi = (dz * 3 + 0) * 3;
                            res01[kl][0] = fmaf(W3[wi], vl, fmaf(W3[wi+1], v, fmaf(W3[wi+2], vr, res01[kl][0])));
                        } else {                        // jr==3: row1 only, dy=2
                            const int wi = (dz * 3 + 2) * 3;
                            res01[kl][1] = fmaf(W3[wi], vl, fmaf(W3[wi+1], v, fmaf(W3[wi+2], vr, res01[kl][1])));
                        }
                    }
                }
            }
        }
        if (lane < W_) {
            const ush4 q0 = *(const ush4*)&sg0[lane * SGPT + c4];   // 4 gates, one b64
            const ush4 q1 = *(const ush4*)&sg1[lane * SGPT + c4];
            #pragma unroll
            for (int kk = 0; kk < 4; ++kk) {
                const int c = c4 + kk;
                const size_t xi = ((size_t)c * H_ + h0) * W_ + lane;
                outb[xi]      = fmaf(res01[kk][0], bf2f(q0[kk]) * invS0, xm0[kk]);
                outb[xi + W_] = fmaf(res01[kk][1], bf2f(q1[kk]) * invS1, xm1[kk]);
            }
        }
    }
}

// ---------- K3: fused CP-reconstruct + softmax + conv3d gate ----------
__global__ __launch_bounds__(1024)
void k_main(
    const float* __restrict__ x,
    const float* __restrict__ Wc, const float* __restrict__ acp,
    const float* __restrict__ Ww, const float* __restrict__ awp,
    const float* __restrict__ Wh, const float* __restrict__ ahp,
    const float* __restrict__ W3,
    const float* __restrict__ gapc, const float* __restrict__ gw,
    const float* __restrict__ gh,
    float* __restrict__ out)
{
    __shared__ __align__(16) char smem[SMEM_SZ];
    unsigned short* sg0   = (unsigned short*)(smem + OFF_SG0T);
    unsigned short* scout = (unsigned short*)(smem + OFF_SCOUT);
    unsigned short* sg1   = scout;                          // alias, post-bar2
    unsigned short* swout = (unsigned short*)(smem + OFF_SWOUT);
    float* sred0 = (float*)(smem + OFF_SRED0);              // alias swout
    float* sred1 = (float*)(smem + OFF_SRED1);
    float* shout = (float*)(smem + OFF_SHOUT);

    // swizzled decode: blocks round-robin XCDs; each XCD owns 4 whole batches
    const int bid  = blockIdx.x;
    const int slot = bid >> 3;
    const int b    = (bid & 7) * 4 + slot / NHT;
    const int h0   = (slot % NHT) * 2;

    const int tid  = threadIdx.x;
    const int lane = tid & 63;
    const int wid  = tid >> 6;
    const int g    = lane >> 4;
    const int col  = lane & 15;
    const int lw   = (lane < W_) ? lane : (W_ - 1);
    const float ac = acp[0], aw = awp[0], ah = ahp[0];

    // ----- staging: one c (or w) per thread; factor rows from GAP results -----
    {   // scout: c = tid>>2 (0..255), r = (tid&3)*16 .. +15
        const float* gc = gapc + b * C_;
        const int c  = tid >> 2;
        const int rq = tid & 3;
        const float gm = (c >= 1)      ? gc[c - 1] : 0.f;
        const float g0 = gc[c];
        const float gp = (c < C_ - 1)  ? gc[c + 1] : 0.f;
        const float* wc = Wc + rq * 48;
        unsigned short* dst = &scout[c * CPH + rq * 16];
        #pragma unroll
        for (int i = 0; i < 16; i += 4) {
            f32x4 vv;
            #pragma unroll
            for (int k = 0; k < 4; ++k) {
                float v = wc[(i+k)*3+0] * gm + wc[(i+k)*3+1] * g0 + wc[(i+k)*3+2] * gp;
                vv[k] = (v >= 0.f) ? v : ac * v;
            }
            u32x2 pkd = { pkbf(vv[0], vv[1]), pkbf(vv[2], vv[3]) };
            *(u32x2*)&dst[i] = pkd;
        }
    }
    {   // swout: w = tid>>4 (0..63), r = (tid&15)*4 .. +3
        const float* gwb = gw + b * W_;
        const int w  = tid >> 4;
        const int rq = tid & 15;
        float gm = 0.f, g0 = 0.f, gp = 0.f;
        if (w < W_) {
            gm = (w >= 1)     ? gwb[w - 1] * (1.f / CH_) : 0.f;
            g0 = gwb[w] * (1.f / CH_);
            gp = (w < W_ - 1) ? gwb[w + 1] * (1.f / CH_) : 0.f;
        }
        const float* ww = Ww + rq * 12;
        f32x4 vv;
        #pragma unroll
        for (int k = 0; k < 4; ++k) {
            float v = ww[k*3+0] * gm + ww[k*3+1] * g0 + ww[k*3+2] * gp;
            vv[k] = (v >= 0.f) ? v : aw * v;
        }
        u32x2 pkd = { pkbf(vv[0], vv[1]), pkbf(vv[2], vv[3]) };
        *(u32x2*)&swout[w * CPH + rq * 4] = pkd;
    }
    if (tid < 2 * 64) {   // shout (f32)
        const float* ghb = gh + b * H_;
        const int hr = tid >> 6, r = tid & 63;
        const int h = h0 + hr;
        const float gm = (h >= 1)     ? ghb[h - 1] * (1.f / CH_) : 0.f;
        const float g0 = ghb[h] * (1.f / CH_);
        const float gp = (h < H_ - 1) ? ghb[h + 1] * (1.f / CH_) : 0.f;
        float v = Wh[r * 3 + 0] * gm + Wh[r * 3 + 1] * g0 + Wh[r * 3 + 2] * gp;
        shout[hr * CPH + r] = (v >= 0.f) ? v : ah * v;
    }
    __syncthreads();                                        // bar1

    const int cbase = wid * 16;
    const int crow  = cbase + col;
    const int cr    = cbase + g * 4;

    // ----- MFMA both rows fused: one fragment read feeds 2 MFMAs -----
    f32x4 acc[8];                   // 0-3: row0 tiles t=0..3; 4-7: row1
    #pragma unroll
    for (int t = 0; t < 8; ++t) acc[t] = (f32x4){0,0,0,0};
    #pragma unroll
    for (int kc = 0; kc < 2; ++kc) {
        const int r0 = kc * 32 + g * 4;
        f32x4 ca = bf2f4(*(ush4*)&scout[crow * CPH + r0]);
        f32x4 cb = bf2f4(*(ush4*)&scout[crow * CPH + r0 + 16]);
        f32x4 ha0 = *(f32x4*)&shout[0 * CPH + r0];
        f32x4 hb0 = *(f32x4*)&shout[0 * CPH + r0 + 16];
        f32x4 ha1 = *(f32x4*)&shout[1 * CPH + r0];
        f32x4 hb1 = *(f32x4*)&shout[1 * CPH + r0 + 16];
        s16x8 af0 = pack8(ca * ha0, cb * hb0);
        s16x8 af1 = pack8(ca * ha1, cb * hb1);
        #pragma unroll
        for (int t = 0; t < 4; ++t) {
            s16x8 bfr = cat8(*(ush4*)&swout[(t*16+col)*CPH + r0],
                             *(ush4*)&swout[(t*16+col)*CPH + r0 + 16]);
            acc[t]     = __builtin_amdgcn_mfma_f32_16x16x32_bf16(af0, bfr, acc[t],     0, 0, 0);
            acc[4 + t] = __builtin_amdgcn_mfma_f32_16x16x32_bf16(af1, bfr, acc[4 + t], 0, 0, 0);
        }
    }
    // exp + wave-partial sums (f32 butterfly); write row0 e-tile to sg0
    float s0p, s1p;
    {
        float st0[4], st1[4];
        #pragma unroll
        for (int t = 0; t < 4; ++t) {
            #pragma unroll
            for (int j = 0; j < 4; ++j) { acc[t][j] = __expf(acc[t][j]); acc[4+t][j] = __expf(acc[4+t][j]); }
            float s0 = acc[t][0] + acc[t][1] + acc[t][2] + acc[t][3];
            float s1 = acc[4+t][0] + acc[4+t][1] + acc[4+t][2] + acc[4+t][3];
            s0 += __shfl_xor(s0, 16, 64);  s0 += __shfl_xor(s0, 32, 64);
            s1 += __shfl_xor(s1, 16, 64);  s1 += __shfl_xor(s1, 32, 64);
            st0[t] = s0; st1[t] = s1;
        }
        s0p = (g == 0) ? st0[0] : (g == 1) ? st0[1] : (g == 2) ? st0[2] : st0[3];
        s1p = (g == 0) ? st1[0] : (g == 1) ? st1[1] : (g == 2) ? st1[2] : st1[3];
        #pragma unroll
        for (int t = 0; t < 4; ++t) {
            const int w = t * 16 + col;
            if (w < W_) {
                u32x2 pkd = { pkbf(acc[t][0], acc[t][1]), pkbf(acc[t][2], acc[t][3]) };
                *(u32x2*)&sg0[w * SGPT + cr] = pkd;
            }
        }
    }
    __syncthreads();                                        // bar2: scout/swout reads done
    {
        #pragma unroll
        for (int t = 0; t < 4; ++t) {
            const int w = t * 16 + col;
            if (w < W_) {
                u32x2 pkd = { pkbf(acc[4+t][0], acc[4+t][1]), pkbf(acc[4+t][2], acc[4+t][3]) };
                *(u32x2*)&sg1[w * SGPT + cr] = pkd;
            }
        }
        sred0[wid * 64 + lane] = s0p;
        sred1[wid * 64 + lane] = s1p;
    }
    __syncthreads();                                        // bar3

    float invS0, invS1;
    {
        float T0 = 0.f, T1 = 0.f;
        #pragma unroll
        for (int t = 0; t < 16; ++t) {
            T0 += sred0[t * 64 + lane];
            T1 += sred1[t * 64 + lane];
        }
        invS0 = 1.f / T0;
        invS1 = 1.f / T1;
    }

    const float* xb = x + (size_t)b * C_ * HW_;
    float* outb = out + (size_t)b * C_ * HW_;
    if (h0 == 0 || h0 == H_ - 2)
        conv_store<true >(xb, W3, sg0, sg1, invS0, invS1, h0, cbase, lane, lw, outb);
    else
        conv_store<false>(xb, W3, sg0, sg1, invS0, invS1, h0, cbase, lane, lw, outb);
}

extern "C" void kernel_launch(void* const* d_in, const int* in_sizes, int n_in,
                              void* d_out, int out_size, void* d_ws, size_t ws_size,
                              hipStream_t stream) {
    const float* x  = (const float*)d_in[0];
    const float* Wc = (const float*)d_in[1];
    const float* ac = (const float*)d_in[2];
    const float* Ww = (const float*)d_in[3];
    const float* aw = (const float*)d_in[4];
    const float* Wh = (const float*)d_in[5];
    const float* ah = (const float*)d_in[6];
    const float* W3 = (const float*)d_in[7];
    float* out  = (float*)d_out;
    float* gapc = (float*)d_ws;                 // B*C
    float* gwp  = gapc + B_ * C_;               // B*W (raw sums)
    float* ghp  = gwp + B_ * W_;                // B*H (raw sums)

    (void)hipMemsetAsync(gwp, 0, (size_t)(B_ * W_ + B_ * H_) * sizeof(float), stream);
    k_reduce<<<dim3(B_ * (C_ / CGRP)), dim3(832), 0, stream>>>(x, gapc, gwp, ghp);
    k_main<<<dim3(B_ * NHT), dim3(1024), 0, stream>>>(
        x, Wc, ac, Ww, aw, Wh, ah, W3, gapc, gwp, ghp, out);
}